// Round 9
// baseline (1258.979 us; speedup 1.0000x reference)
//
#include <hip/hip_runtime.h>
#include <stdio.h>
#include <stdint.h>

typedef __attribute__((ext_vector_type(8))) short short8;     // 8 x bf16 bits (4 VGPRs)
typedef __attribute__((ext_vector_type(4))) float f32x4;      // MFMA accum
typedef __attribute__((ext_vector_type(4))) unsigned short ushort4v;

__device__ __forceinline__ unsigned short f2bf(float f) {
  unsigned int u = __builtin_bit_cast(unsigned int, f);
  u = u + 0x7FFFu + ((u >> 16) & 1u);   // RNE
  return (unsigned short)(u >> 16);
}
__device__ __forceinline__ float bf2f(unsigned short h) {
  unsigned int u = ((unsigned int)h) << 16;
  return __builtin_bit_cast(float, u);
}

// async global->LDS, 16B per lane; LDS dest = wave-uniform base + lane*16
__device__ __forceinline__ void gl_lds16(const unsigned short* g, unsigned short* l) {
  __builtin_amdgcn_global_load_lds(
      (const __attribute__((address_space(1))) unsigned int*)(const void*)g,
      (__attribute__((address_space(3))) unsigned int*)(void*)l, 16, 0, 0);
}

#define RAW_BAR()  asm volatile("s_barrier" ::: "memory")
#define LGKM0()    asm volatile("s_waitcnt lgkmcnt(0)" ::: "memory")
#define VMCNT(n_)  asm volatile("s_waitcnt vmcnt(" #n_ ")" ::: "memory")

// -------- tiled transpose+cast (+zero pad): out[n][k] = f2bf(in[k][n]); coalesced both sides --------
__global__ void k_transpose_cast_t(const float* __restrict__ in, unsigned short* __restrict__ out,
                                   int Nin, int Kin, int ldo) {
  __shared__ float lds[64][65];
  int k0 = blockIdx.x * 64, n0 = blockIdx.y * 64;
  int t = threadIdx.x, tc = t & 15, tr = t >> 4;
  #pragma unroll
  for (int rr = 0; rr < 4; ++rr) {
    int kl = tr + rr * 16, k = k0 + kl;
    #pragma unroll
    for (int j = 0; j < 4; ++j) {
      int nl = tc * 4 + j, n = n0 + nl;
      lds[kl][nl] = (k < Kin && n < Nin) ? in[(size_t)k * Nin + n] : 0.f;
    }
  }
  __syncthreads();
  #pragma unroll
  for (int rr = 0; rr < 4; ++rr) {
    int nl = tr + rr * 16, n = n0 + nl;
    int kb = k0 + tc * 4;
    if (kb + 3 < ldo) {
      ushort4v o;
      o.x = f2bf(lds[tc * 4 + 0][nl]);
      o.y = f2bf(lds[tc * 4 + 1][nl]);
      o.z = f2bf(lds[tc * 4 + 2][nl]);
      o.w = f2bf(lds[tc * 4 + 3][nl]);
      *(ushort4v*)&out[(size_t)n * ldo + kb] = o;
    } else {
      for (int j = 0; j < 4; ++j)
        if (kb + j < ldo) out[(size_t)n * ldo + kb + j] = f2bf(lds[tc * 4 + j][nl]);
    }
  }
}

// ---------------- att layer 1: h = relu(t[b]*W2a[j] + b2a[j]) -> bf16 [2048x1024] ----------------
__global__ void k_att_l1(const float* __restrict__ tar, const float* __restrict__ W2a,
                         const float* __restrict__ b2a, unsigned short* __restrict__ out) {
  int id = blockIdx.x * 256 + threadIdx.x;   // 2048*1024
  int b = id >> 10, j = id & 1023;
  out[id] = f2bf(fmaxf(tar[b] * W2a[j] + b2a[j], 0.f));
}

// ---------------- v2s cast to bf16, K padded 312->320 ----------------
__global__ void k_v2s_cast(const float* __restrict__ v2s, unsigned short* __restrict__ out) {
  int id = blockIdx.x * 256 + threadIdx.x;   // 2048*320
  int r = id / 320, c = id - r * 320;
  out[id] = (c < 312) ? f2bf(v2s[(size_t)r * 312 + c]) : (unsigned short)0;
}

// ====== 128x128 bf16 GEMM, 3-LDS-buf + register-double-banked pipeline ======
// Mechanism fix vs R4-R8 (all ~36% MFMA): frag ds_reads for tile t+1 are issued BEFORE tile
// t's MFMA cluster (other reg bank), so the LDS-port backlog (~400cyc/block) drains under the
// MFMA shadow instead of serializing with it.
// Schedule (iter t): STAGE(t+3)->buf[t%3]; READF frags(t+1)<-buf[(t+1)%3]; MFMA frags(t);
//   lgkm0 (WAR fence: my reads complete before anyone's next-iter stage overwrite);
//   vmcnt: end of iter u drains stage(u+2) [4 newest = stage(u+3) stay] -> reads at u+1 safe;
//   tail: if u+3>=NT nothing newer outstanding -> vmcnt(0). raw s_barrier (no implicit drain).
// WAR proof: stage(t+3) writes buf[t%3]; its last reads (frags(t), iter t-1) completed at the
// lgkm0 before the barrier ending iter t-1; stage issues after that barrier.
// Requires NT even and NT >= 4 (K in {320,1024,2048} -> NT 10/32/64).
__device__ __forceinline__ int lds_off(int row, int g) {
  int slot = (g + (row >> 1)) & 3;
  return row * 32 + slot * 8;                 // ushort units, ld=32
}

template<bool RELU, bool OUTBF16>
__global__ __launch_bounds__(256)
void k_gemm_bt(const unsigned short* __restrict__ A, const unsigned short* __restrict__ B,
               const float* __restrict__ bias, int bias_n, int nNt, int N_store, int K,
               void* __restrict__ outp, int ldo, int remap) {
  __shared__ __align__(16) unsigned short As[3][4096];   // 3 bufs x (128 rows x 32) = 24KB
  __shared__ __align__(16) unsigned short Bs[3][4096];   // 48KB total -> 3 blocks/CU
  int d = blockIdx.x, nwg = gridDim.x;
  int L = d;
  if (remap) { int q = nwg >> 3; L = (d & 7) * q + (d >> 3); }  // only used when nwg % 8 == 0
  int mt = L / nNt, nt = L - mt * nNt;
  size_t m0 = (size_t)mt * 128, n0 = (size_t)nt * 128;
  int tid = threadIdx.x, lane = tid & 63;
  int w = tid >> 6, wr = w >> 1, wc = w & 1;
  int sr = tid >> 2;
  int gch = ((tid & 3) - (tid >> 3)) & 3;     // pre-swizzled global chunk (rule #21)
  const unsigned short* pA0 = A + (m0 + sr) * K + gch * 8;
  const unsigned short* pA1 = pA0 + (size_t)64 * K;
  const unsigned short* pB0 = B + (n0 + sr) * K + gch * 8;
  const unsigned short* pB1 = pB0 + (size_t)64 * K;
  int sd = (tid & ~63) * 8;                   // wave-uniform dest; HW adds lane*16B

  int kg = lane >> 4, l15 = lane & 15;
  int aoff = lds_off(wr * 64 + l15, kg);
  int boff = lds_off(wc * 64 + l15, kg);

  f32x4 acc[4][4];
  #pragma unroll
  for (int i = 0; i < 4; ++i)
    #pragma unroll
    for (int j = 0; j < 4; ++j) acc[i][j] = (f32x4)(0.f);

  const int NT = K >> 5;                      // even, >= 4 at all call sites
#define STAGE(t_, b_) do { int k0_ = (t_) * 32;                       \
    gl_lds16(pA0 + k0_, &As[b_][sd]);                                 \
    gl_lds16(pA1 + k0_, &As[b_][2048 + sd]);                          \
    gl_lds16(pB0 + k0_, &Bs[b_][sd]);                                 \
    gl_lds16(pB1 + k0_, &Bs[b_][2048 + sd]);                          \
  } while (0)
#define READF(b_, fa_, fb_) do {                                                  \
    _Pragma("unroll")                                                             \
    for (int mi = 0; mi < 4; ++mi) fa_[mi] = *(const short8*)&As[b_][aoff + mi * 512]; \
    _Pragma("unroll")                                                             \
    for (int ni = 0; ni < 4; ++ni) fb_[ni] = *(const short8*)&Bs[b_][boff + ni * 512]; \
  } while (0)
#define MFMAC(fa_, fb_) do {                                                      \
    __builtin_amdgcn_s_setprio(1);                                                \
    _Pragma("unroll")                                                             \
    for (int mi = 0; mi < 4; ++mi)                                                \
      _Pragma("unroll")                                                           \
      for (int ni = 0; ni < 4; ++ni)                                              \
        acc[mi][ni] = __builtin_amdgcn_mfma_f32_16x16x32_bf16(fa_[mi], fb_[ni], acc[mi][ni], 0, 0, 0); \
    __builtin_amdgcn_s_setprio(0);                                                \
  } while (0)

  // prologue: fill 3 buffers; vmcnt(4) drains stages 0,1 (keeps 4 newest = stage 2)
  STAGE(0, 0); STAGE(1, 1); STAGE(2, 2);
  VMCNT(4); RAW_BAR();
  short8 ea[4], ebv[4], oa[4], obv[4];
  READF(0, ea, ebv);                          // frags(0) -> even bank
  LGKM0();                                    // reads complete before iter0's STAGE(3)->buf0
  RAW_BAR();

  int bA = 0, bB = 1, bC = 2;                 // bA=t%3, bB=(t+1)%3, bC=(t+2)%3
  for (int t = 0; t < NT; t += 2) {
    // ---- even iter t: MFMA even bank, read odd bank (frags t+1), stage t+3 -> bA
    if (t + 3 < NT) STAGE(t + 3, bA);
    if (t + 1 < NT) READF(bB, oa, obv);
    MFMAC(ea, ebv);
    LGKM0();
    if (t + 3 < NT) { VMCNT(4); } else { VMCNT(0); }
    RAW_BAR();
    // ---- odd iter t+1: MFMA odd bank, read even bank (frags t+2), stage t+4 -> bB
    if (t + 4 < NT) STAGE(t + 4, bB);
    if (t + 2 < NT) READF(bC, ea, ebv);
    MFMAC(oa, obv);
    LGKM0();
    if (t + 4 < NT) { VMCNT(4); } else { VMCNT(0); }
    RAW_BAR();
    // rotate buffers by 2: (bA,bB,bC) <- (bC,bA,bB)
    int tmp = bC; bC = bB; bB = bA; bA = tmp;
  }
#undef STAGE
#undef READF
#undef MFMAC

  #pragma unroll
  for (int ni = 0; ni < 4; ++ni) {
    int colg = (int)n0 + wc * 64 + ni * 16 + l15;
    if (colg < N_store) {
      float bs = bias ? (colg < bias_n ? bias[colg] : 0.f) : 0.f;
      #pragma unroll
      for (int mi = 0; mi < 4; ++mi) {
        #pragma unroll
        for (int r2 = 0; r2 < 4; ++r2) {
          size_t rowg = m0 + wr * 64 + mi * 16 + kg * 4 + r2;   // C/D: row=(l>>4)*4+r, col=l&15
          float v = acc[mi][ni][r2] + bs;
          if (RELU) v = fmaxf(v, 0.f);
          if (OUTBF16) ((unsigned short*)outp)[rowg * ldo + colg] = f2bf(v);
          else         ((float*)outp)[rowg * ldo + colg] = v;
        }
      }
    }
  }
}

// ------- H1c[r_local] = relu(V1[src] + A1p[arow]) -> bf16  (b1a pre-folded into A1p) -------
__global__ void k_build_h1(const float* __restrict__ V1, const float* __restrict__ A1p,
                           const int* __restrict__ idx, unsigned short* __restrict__ H1c,
                           int rbase) {
  int row = rbase + blockIdx.x;                // global row 0..133119
  int src, arow;
  if (row < 2048) { src = row; arow = row; }   // rows 0..2047 = query
  else {
    int g = row - 2048; arow = g >> 6;
    int s = idx[g];
    src = s < 0 ? 0 : (s > 2047 ? 2047 : s);
  }
  int j = threadIdx.x * 4;
  float4 v = *(const float4*)(V1 + (size_t)src * 1024 + j);
  float4 a = *(const float4*)(A1p + (size_t)arow * 1024 + j);
  ushort4v o;
  o.x = f2bf(fmaxf(v.x + a.x, 0.f));
  o.y = f2bf(fmaxf(v.y + a.y, 0.f));
  o.z = f2bf(fmaxf(v.z + a.z, 0.f));
  o.w = f2bf(fmaxf(v.w + a.w, 0.f));
  *(ushort4v*)(H1c + (size_t)blockIdx.x * 1024 + j) = o;
}

// ---------------- logits[b,k] = dot(P[b], P[2048 + b*64 + k]) / T  (P is bf16) ----------------
__global__ void k_dot(const unsigned short* __restrict__ P, float* __restrict__ out) {
  __shared__ float q[128];
  int b = blockIdx.x, t = threadIdx.x;
  if (t < 128) q[t] = bf2f(P[(size_t)b * 128 + t]);
  __syncthreads();
  int k = t >> 2, part = t & 3;
  const unsigned short* row = P + (size_t)(2048 + b * 64 + k) * 128 + part * 32;
  const float* qp = q + part * 32;
  float s = 0.f;
  #pragma unroll
  for (int j = 0; j < 32; j += 8) {
    short8 pv = *(const short8*)(row + j);
    #pragma unroll
    for (int e = 0; e < 8; ++e)
      s += bf2f((unsigned short)pv[e]) * qp[j + e];
  }
  s += __shfl_xor(s, 1);
  s += __shfl_xor(s, 2);
  if (part == 0) out[(size_t)b * 64 + k] = s * (float)(1.0 / 0.12);
}

extern "C" void kernel_launch(void* const* d_in, const int* in_sizes, int n_in,
                              void* d_out, int out_size, void* d_ws, size_t ws_size,
                              hipStream_t stream) {
  const float* v2s = (const float*)d_in[0];
  const float* tar = (const float*)d_in[1];
  const int*   sidx = (const int*)d_in[2];
  const float* W2a = (const float*)d_in[3];
  const float* b2a = (const float*)d_in[4];
  const float* W2b = (const float*)d_in[5];
  const float* b2b = (const float*)d_in[6];
  const float* W2c = (const float*)d_in[7];
  const float* b2c = (const float*)d_in[8];
  const float* W1a = (const float*)d_in[9];
  const float* b1a = (const float*)d_in[10];
  const float* W1b = (const float*)d_in[11];
  const float* b1b = (const float*)d_in[12];
  const float* W1c = (const float*)d_in[13];
  const float* b1c = (const float*)d_in[14];
  float* out = (float*)d_out;

  char* ws = (char*)d_ws;
  size_t off = 0;
  auto alloc = [&](size_t bytes) -> char* {
    char* p = ws + off; off += (bytes + 255) & ~(size_t)255; return p;
  };
  // persistent
  unsigned short* W1bT = (unsigned short*)alloc(2048ull * 1024 * 2);  // [2048][1024]
  unsigned short* W1cT = (unsigned short*)alloc(128ull * 2048 * 2);   // [128][2048]
  float*          V1   = (float*)alloc(2048ull * 1024 * 4);           // v2s @ W1a
  float*          A1p  = (float*)alloc(2048ull * 1024 * 4);           // att @ W1a + b1a
  unsigned short* Pb   = (unsigned short*)alloc(133120ull * 128 * 2); // bf16 projections
  // overlay
  size_t O = off;
  off = O;
  unsigned short* W1aT = (unsigned short*)alloc(1024ull * 320 * 2);   // [1024][320]  (K-pad)
  unsigned short* v2sb = (unsigned short*)alloc(2048ull * 320 * 2);
  unsigned short* attb = (unsigned short*)alloc(2048ull * 320 * 2);
  unsigned short* W2bT = (unsigned short*)alloc(2048ull * 1024 * 2);
  unsigned short* W2cT = (unsigned short*)alloc(384ull * 2048 * 2);   // [384][2048]  (N-pad)
  unsigned short* h_a  = (unsigned short*)alloc(2048ull * 1024 * 2);
  unsigned short* h2a  = (unsigned short*)alloc(2048ull * 2048 * 2);
  size_t early_end = off;

  // ---- chunk plans: m-tiles (x256 rows) per chunk, sum = 520 (all row counts % 128 == 0)
  static const int plans[4][8] = {{260,260,0,0,0,0,0,0},
                                  {132,132,128,128,0,0,0,0},
                                  {130,130,130,130,0,0,0,0},
                                  {65,65,65,65,65,65,65,65}};
  int sel = -1, maxmt = 0;
  for (int p = 0; p < 4 && sel < 0; ++p) {
    int mx = 0;
    for (int i = 0; i < 8; ++i) if (plans[p][i] > mx) mx = plans[p][i];
    size_t rows = (size_t)mx * 256;
    size_t late = O + ((rows * 1024 * 2 + 255) & ~(size_t)255)
                    + ((rows * 2048 * 2 + 255) & ~(size_t)255);
    size_t need = late > early_end ? late : early_end;
    if (need <= ws_size) { sel = p; maxmt = mx; }
  }
  int fallR = 0;
  if (sel < 0) {   // NCH=16 fallback
    size_t rows = 133120ull / 16;
    size_t late = O + ((rows * 1024 * 2 + 255) & ~(size_t)255)
                    + ((rows * 2048 * 2 + 255) & ~(size_t)255);
    size_t need = late > early_end ? late : early_end;
    if (need <= ws_size) fallR = (int)rows;
  }
  fprintf(stderr, "[kernel_launch] ws_size=%zu sel=%d\n", ws_size, sel);
  if (sel < 0 && !fallR) {
    hipMemsetAsync(d_out, 0, (size_t)out_size * 4, stream);
    return;
  }
  off = O;
  size_t bufrows = (sel >= 0) ? (size_t)maxmt * 256 : (size_t)fallR;
  unsigned short* H1c = (unsigned short*)alloc(bufrows * 1024 * 2);
  unsigned short* H2c = (unsigned short*)alloc(bufrows * 2048 * 2);

  dim3 blk(256);
  // weight prep (tiled coalesced transpose)
  k_transpose_cast_t<<<dim3(16, 32), blk, 0, stream>>>(W2b, W2bT, 2048, 1024, 1024);
  k_transpose_cast_t<<<dim3(32, 6),  blk, 0, stream>>>(W2c, W2cT, 312, 2048, 2048);
  k_transpose_cast_t<<<dim3(5, 16),  blk, 0, stream>>>(W1a, W1aT, 1024, 312, 320);
  k_transpose_cast_t<<<dim3(16, 32), blk, 0, stream>>>(W1b, W1bT, 2048, 1024, 1024);
  k_transpose_cast_t<<<dim3(32, 2),  blk, 0, stream>>>(W1c, W1cT, 128, 2048, 2048);
  k_att_l1<<<8192, blk, 0, stream>>>(tar, W2a, b2a, h_a);
  k_v2s_cast<<<2560, blk, 0, stream>>>(v2s, v2sb);
  // att MLP
  k_gemm_bt<true,  true ><<<256, blk, 0, stream>>>(h_a,  W2bT, b2b, 2048, 16, 2048, 1024, h2a,  2048, 1);
  k_gemm_bt<true,  true ><<<48,  blk, 0, stream>>>(h2a,  W2cT, b2c, 312,  3,  320,  2048, attb, 320,  1);
  // layer-1 factored
  k_gemm_bt<false, false><<<128, blk, 0, stream>>>(v2sb, W1aT, nullptr, 0,  8, 1024, 320, V1,  1024, 1);
  k_gemm_bt<false, false><<<128, blk, 0, stream>>>(attb, W1aT, b1a, 1024,  8, 1024, 320, A1p, 1024, 1);
  // chunked: build H1 -> layer2 -> layer3
  if (sel >= 0) {
    int rbase = 0;
    for (int i = 0; i < 8 && plans[sel][i]; ++i) {
      int R = plans[sel][i] * 256;
      k_build_h1<<<R, blk, 0, stream>>>(V1, A1p, sidx, H1c, rbase);
      k_gemm_bt<true, true><<<(R / 128) * 16, blk, 0, stream>>>(H1c, W1bT, b1b, 2048, 16, 2048, 1024, H2c, 2048, 1);
      k_gemm_bt<true, true><<<(R / 128), blk, 0, stream>>>(H2c, W1cT, b1c, 128, 1, 128, 2048,
                                                            Pb + (size_t)rbase * 128, 128, 0);
      rbase += R;
    }
  } else {
    for (int c = 0; c < 16; ++c) {
      int rbase = c * fallR;
      k_build_h1<<<fallR, blk, 0, stream>>>(V1, A1p, sidx, H1c, rbase);
      k_gemm_bt<true, true><<<(fallR / 128) * 16, blk, 0, stream>>>(H1c, W1bT, b1b, 2048, 16, 2048, 1024, H2c, 2048, 1);
      k_gemm_bt<true, true><<<(fallR / 128), blk, 0, stream>>>(H2c, W1cT, b1c, 128, 1, 128, 2048,
                                                                Pb + (size_t)rbase * 128, 128, 0);
    }
  }
  // logits
  k_dot<<<2048, blk, 0, stream>>>(Pb, out);
}